// Round 11
// baseline (358.179 us; speedup 1.0000x reference)
//
#include <hip/hip_runtime.h>

#define N_NODES 50000
#define N_EDGES 800000
#define IN_DIM  1200
#define KP      1216               // Wb padded K
#define OUT_DIM 300
#define BNP     320                // Wb padded rows
#define XBS     304                // xb row stride (bf16)
#define BM      64
#define NKT     38                 // K-steps of 32
#define GRID_M  ((N_NODES + BM - 1) / BM)   // 782
#define GRID_G  (GRID_M * 2)                // 1564 (x 2 N-halves)

typedef __attribute__((ext_vector_type(8))) short short8;
typedef __attribute__((ext_vector_type(4))) float f32x4;

__device__ __forceinline__ short f2bf(float f) {
  unsigned u = __builtin_bit_cast(unsigned, f);
  u += 0x7fffu + ((u >> 16) & 1u);            // RNE
  return (short)(u >> 16);
}
__device__ __forceinline__ float bf2f(unsigned short h) {
  return __builtin_bit_cast(float, (unsigned)h << 16);
}
__device__ __forceinline__ float lrelu(float v) { return v > 0.f ? v : 0.2f * v; }

__device__ __forceinline__ float wredMaxF(float v) {
  #pragma unroll
  for (int o = 32; o > 0; o >>= 1) v = fmaxf(v, __shfl_xor(v, o));
  return v;
}
__device__ __forceinline__ float wredSumF(float v) {
  #pragma unroll
  for (int o = 32; o > 0; o >>= 1) v += __shfl_xor(v, o);
  return v;
}

// async 16B/lane global->LDS DMA; lds dest wave-uniform (HW adds lane*16)
__device__ __forceinline__ void gl_lds16(const unsigned short* g, unsigned short* l) {
  __builtin_amdgcn_global_load_lds(
      (const __attribute__((address_space(1))) unsigned int*)g,
      (__attribute__((address_space(3))) unsigned int*)l, 16, 0, 0);
}

// ---------------- W -> bf16, padded [320][1216]
__global__ __launch_bounds__(256) void wconv(const float* __restrict__ W,
                                             unsigned short* __restrict__ Wb) {
  int f = blockIdx.x * 256 + threadIdx.x;
  if (f >= BNP * KP / 8) return;
  int n = (f * 8) / KP, c = (f * 8) % KP;
  short8 v = {0,0,0,0,0,0,0,0};
  if (n < OUT_DIM && c < IN_DIM) {
    const float4* p = reinterpret_cast<const float4*>(W + (size_t)n * IN_DIM + c);
    float4 f0 = p[0], f1 = p[1];
    v[0]=f2bf(f0.x); v[1]=f2bf(f0.y); v[2]=f2bf(f0.z); v[3]=f2bf(f0.w);
    v[4]=f2bf(f1.x); v[5]=f2bf(f1.y); v[6]=f2bf(f1.z); v[7]=f2bf(f1.w);
  }
  *reinterpret_cast<short8*>(&Wb[(size_t)n * KP + c]) = v;
}

// ---------------- GEMM: xb = z @ W^T. BM=64, BN=160/block (2 N-half blocks),
// BK=32, 4 waves = 2Mw x 2Nw; wave = 2M x 5N frags. LDS 28 KB -> 4-5 blocks/CU.
// Bijective XCD swizzle puts the two N-halves of an M-tile on the SAME XCD
// (z tile L2-reuse). Logits epilogue: 2-term atomicAdd (commutative-exact).
__global__ __launch_bounds__(256) void gemm_x(const float* __restrict__ z,
                                              const unsigned short* __restrict__ Wb,
                                              const float* __restrict__ att_s,
                                              const float* __restrict__ att_d,
                                              unsigned short* __restrict__ xb,
                                              float* __restrict__ a_s,
                                              float* __restrict__ a_d) {
  __shared__ __align__(16) unsigned short As[2][BM * 32];     // 2 x 4 KB
  __shared__ __align__(16) unsigned short Bs[2][160 * 32];    // 2 x 10 KB

  // bijective XCD swizzle (nwg=1564: q=195, r=4): same-XCD origs -> contiguous
  // logical range, so logical pairs (2k,2k+1) share an XCD and are time-adjacent.
  const int orig = blockIdx.x;
  const int xcd  = orig & 7, rem = orig >> 3;
  const int base = (xcd < 4) ? xcd * 196 : 784 + (xcd - 4) * 195;
  const int logical = base + rem;
  const int m0 = (logical >> 1) * BM;
  const int n0 = (logical & 1) * 160;

  const int tid  = threadIdx.x;
  const int lane = tid & 63;
  const int wid  = tid >> 6;
  const int lr   = lane & 15;
  const int lg   = lane >> 4;
  const int lrs  = (lr >> 1) & 3;      // read-side swizzle term
  const int mw   = wid >> 1;           // 0..1: rows mw*32..
  const int nw   = wid & 1;            // 0..1: cols n0+nw*80..

  f32x4 zero4 = {0.f, 0.f, 0.f, 0.f};
  const float4 fz4 = make_float4(0.f, 0.f, 0.f, 0.f);
  f32x4 acc[2][5];
  #pragma unroll
  for (int mf = 0; mf < 2; ++mf)
    #pragma unroll
    for (int nj = 0; nj < 5; ++nj) acc[mf][nj] = zero4;

  // A stage: thread -> row ra (0..63), logical chunk kaL, physical kaP
  const int ra  = tid >> 2;
  const int kaL = tid & 3;
  const int kaP = kaL ^ ((ra >> 1) & 3);
  const int am  = m0 + ra;
  float4 ga0, ga1;

  // B DMA: j-group = 16 rows; lane l -> row j*16+(l>>2), phys chunk l&3;
  // global source pre-swizzled: chunk (l&3) ^ ((l>>3)&3).
  const int bgc = (lane & 3) ^ ((lane >> 3) & 3);

  #define LOADA(KT)                                                           \
    {                                                                         \
      int k = (KT) * 32 + kaL * 8;                                            \
      if (am < N_NODES && k + 8 <= IN_DIM) {                                  \
        const float4* p = reinterpret_cast<const float4*>(z + (size_t)am * IN_DIM + k); \
        ga0 = p[0]; ga1 = p[1];                                               \
      } else { ga0 = fz4; ga1 = fz4; }                                        \
    }

  #define WRITEA(BUF)                                                         \
    {                                                                         \
      short8 v;                                                               \
      v[0]=f2bf(ga0.x); v[1]=f2bf(ga0.y); v[2]=f2bf(ga0.z); v[3]=f2bf(ga0.w); \
      v[4]=f2bf(ga1.x); v[5]=f2bf(ga1.y); v[6]=f2bf(ga1.z); v[7]=f2bf(ga1.w); \
      *reinterpret_cast<short8*>(&As[BUF][ra * 32 + kaP * 8]) = v;            \
    }

  #define STAGEB(BUF, KT)                                                     \
    _Pragma("unroll")                                                         \
    for (int j = 0; j < 10; ++j) {                                            \
      if ((j & 3) == wid) {                                                   \
        const unsigned short* gsrc =                                          \
            Wb + (size_t)(n0 + j * 16 + (lane >> 2)) * KP + (KT) * 32 + bgc * 8; \
        gl_lds16(gsrc, &Bs[BUF][j * 16 * 32]);                                \
      }                                                                       \
    }

  STAGEB(0, 0);
  LOADA(0);
  WRITEA(0);
  __syncthreads();

  #pragma unroll 1
  for (int kt = 0; kt < NKT; ++kt) {
    const int cur = kt & 1;
    if (kt < NKT - 1) {
      STAGEB(cur ^ 1, kt + 1);       // async DMA toward other buffer
      LOADA(kt + 1);
    }

    // A frags: row = mw*32 + mf*16 + lr; phys chunk = lg ^ lrs
    short8 a0 = *reinterpret_cast<const short8*>(
        &As[cur][(mw * 32 + lr) * 32 + (lg ^ lrs) * 8]);
    short8 a1 = *reinterpret_cast<const short8*>(
        &As[cur][(mw * 32 + 16 + lr) * 32 + (lg ^ lrs) * 8]);
    // B frags: row = nw*80 + nj*16 + lr
    #pragma unroll
    for (int nj = 0; nj < 5; ++nj) {
      short8 b = *reinterpret_cast<const short8*>(
          &Bs[cur][(nw * 80 + nj * 16 + lr) * 32 + (lg ^ lrs) * 8]);
      acc[0][nj] = __builtin_amdgcn_mfma_f32_16x16x32_bf16(a0, b, acc[0][nj], 0, 0, 0);
      acc[1][nj] = __builtin_amdgcn_mfma_f32_16x16x32_bf16(a1, b, acc[1][nj], 0, 0, 0);
    }

    if (kt < NKT - 1) { WRITEA(cur ^ 1); }
    __syncthreads();                 // drains DMA + A write, releases cur
  }
  #undef LOADA
  #undef WRITEA
  #undef STAGEB

  // ---- epilogue: bf16 x store + partial logits; cross-nw LDS reduce,
  // then one atomicAdd per row (2 blocks/row total: commutative-exact).
  float* red = reinterpret_cast<float*>(&As[0][0]);  // [2 sd][2 nw][64] = 1 KB

  float ps[2][4] = {{0,0,0,0},{0,0,0,0}}, pd[2][4] = {{0,0,0,0},{0,0,0,0}};
  #pragma unroll
  for (int nj = 0; nj < 5; ++nj) {
    int c = n0 + nw * 80 + nj * 16 + lr;
    bool cv = c < OUT_DIM;
    float vs = cv ? att_s[c] : 0.f;
    float vd = cv ? att_d[c] : 0.f;
    #pragma unroll
    for (int mf = 0; mf < 2; ++mf) {
      #pragma unroll
      for (int jj = 0; jj < 4; ++jj) {
        float val = acc[mf][nj][jj];
        int r = m0 + mw * 32 + mf * 16 + 4 * lg + jj;
        if (cv && r < N_NODES) xb[(size_t)r * XBS + c] = (unsigned short)f2bf(val);
        ps[mf][jj] += val * vs;
        pd[mf][jj] += val * vd;
      }
    }
  }
  #pragma unroll
  for (int mf = 0; mf < 2; ++mf)
    #pragma unroll
    for (int jj = 0; jj < 4; ++jj) {
      #pragma unroll
      for (int o = 8; o > 0; o >>= 1) {
        ps[mf][jj] += __shfl_xor(ps[mf][jj], o);
        pd[mf][jj] += __shfl_xor(pd[mf][jj], o);
      }
      if (lr == 0) {
        int rr = mw * 32 + mf * 16 + 4 * lg + jj;
        red[nw * 64 + rr]       = ps[mf][jj];
        red[128 + nw * 64 + rr] = pd[mf][jj];
      }
    }
  __syncthreads();
  if (tid < 64) {
    int r = m0 + tid;
    if (r < N_NODES) atomicAdd(&a_s[r], red[tid] + red[64 + tid]);
  } else if (tid < 128) {
    int t = tid - 64, r = m0 + t;
    if (r < N_NODES) atomicAdd(&a_d[r], red[128 + t] + red[192 + t]);
  }
}

// ---------------- CSR build (edges only; self-loops handled analytically)
__global__ void hist(const int* __restrict__ ei, int* __restrict__ deg) {
  int e = blockIdx.x * blockDim.x + threadIdx.x;
  if (e < N_EDGES) {
    unsigned dst = (unsigned)ei[N_EDGES + e];
    if (dst < N_NODES) atomicAdd(&deg[dst], 1);
  }
}

#define SCAN_B 1024
#define NBLK   49

__global__ __launch_bounds__(SCAN_B) void scan1(const int* __restrict__ deg,
                                                int* __restrict__ bsum) {
  int i = blockIdx.x * SCAN_B + threadIdx.x;
  int v = (i < N_NODES) ? deg[i] : 0;
  #pragma unroll
  for (int o = 32; o > 0; o >>= 1) v += __shfl_xor(v, o);
  __shared__ int wt[16];
  if ((threadIdx.x & 63) == 0) wt[threadIdx.x >> 6] = v;
  __syncthreads();
  if (threadIdx.x == 0) {
    int t = 0;
    #pragma unroll
    for (int w = 0; w < 16; ++w) t += wt[w];
    bsum[blockIdx.x] = t;
  }
}

__global__ void scan2(const int* __restrict__ bsum, int* __restrict__ bex,
                      int* __restrict__ offs) {
  int l = threadIdx.x;
  int v = (l < NBLK) ? bsum[l] : 0;
  int incl = v;
  #pragma unroll
  for (int off = 1; off < 64; off <<= 1) {
    int u = __shfl_up(incl, off);
    if (l >= off) incl += u;
  }
  if (l < NBLK) bex[l] = incl - v;
  if (l == NBLK - 1) offs[N_NODES] = incl;
}

__global__ __launch_bounds__(SCAN_B) void scan3(const int* __restrict__ deg,
                                                const int* __restrict__ bex,
                                                int* __restrict__ offs,
                                                int* __restrict__ cursor) {
  int tid = threadIdx.x;
  int i = blockIdx.x * SCAN_B + tid;
  int lane = tid & 63, wid = tid >> 6;
  int v = (i < N_NODES) ? deg[i] : 0;
  int incl = v;
  #pragma unroll
  for (int off = 1; off < 64; off <<= 1) {
    int u = __shfl_up(incl, off);
    if (lane >= off) incl += u;
  }
  __shared__ int wt[16];
  if (lane == 63) wt[wid] = incl;
  __syncthreads();
  if (tid < 16) {
    int t = wt[tid];
    int sc = t;
    #pragma unroll
    for (int off = 1; off < 16; off <<= 1) {
      int u = __shfl_up(sc, off);
      if (tid >= off) sc += u;
    }
    wt[tid] = sc - t;
  }
  __syncthreads();
  int excl = incl - v + wt[wid] + bex[blockIdx.x];
  if (i < N_NODES) { offs[i] = excl; cursor[i] = excl; }
}

__global__ void fill(const int* __restrict__ ei, int* __restrict__ cursor,
                     int* __restrict__ srcs) {
  int e = blockIdx.x * blockDim.x + threadIdx.x;
  if (e < N_EDGES) {
    unsigned dst = (unsigned)ei[N_EDGES + e];
    unsigned src = (unsigned)ei[e];
    if (dst < N_NODES && src < N_NODES) {
      int pos = atomicAdd(&cursor[dst], 1);
      srcs[pos] = (int)src;
    }
  }
}

// ---------------- per-node softmax stats (m, 1/s) — wave per node
__global__ __launch_bounds__(256) void minv_k(const float* __restrict__ a_s,
                                              const float* __restrict__ a_d,
                                              const int* __restrict__ offs,
                                              const int* __restrict__ srcs,
                                              float2* __restrict__ minv) {
  int node = blockIdx.x * 4 + (threadIdx.x >> 6);
  if (node >= N_NODES) return;
  int lane = threadIdx.x & 63;
  int beg = offs[node], end = offs[node + 1];
  float adi = a_d[node];
  float eself = lrelu(a_s[node] + adi);

  float m = eself;
  for (int k = beg + lane; k < end; k += 64)
    m = fmaxf(m, lrelu(a_s[srcs[k]] + adi));
  m = wredMaxF(m);

  float s = 0.f;
  for (int k = beg + lane; k < end; k += 64)
    s += expf(lrelu(a_s[srcs[k]] + adi) - m);
  s = wredSumF(s) + expf(eself - m);
  if (lane == 0) minv[node] = make_float2(m, 1.0f / s);
}

// ---------------- streaming weighted gather: thread = (node, 20-col chunk)
#define CCH 15
__global__ __launch_bounds__(256) void aggregate(const unsigned short* __restrict__ xb,
                                                 const float* __restrict__ a_s,
                                                 const float* __restrict__ a_d,
                                                 const float2* __restrict__ minv,
                                                 const int* __restrict__ offs,
                                                 const int* __restrict__ srcs,
                                                 const float* __restrict__ bias,
                                                 float* __restrict__ out) {
  unsigned wi = blockIdx.x * 256u + threadIdx.x;
  if (wi >= (unsigned)N_NODES * CCH) return;
  unsigned node = wi / CCH;
  unsigned cc = wi - node * CCH;           // cols 20cc..20cc+19

  int beg = offs[node], end = offs[node + 1];
  float2 mi = minv[node];
  const float m = mi.x, inv = mi.y;
  const float adi = a_d[node];
  const float wself = expf(lrelu(a_s[node] + adi) - m) * inv;

  const unsigned short* xcol = xb + 20u * cc;

  float acc[20];
  {
    const unsigned short* xr = xcol + (size_t)node * XBS;
    #pragma unroll
    for (int q = 0; q < 5; ++q) {
      ushort4 xv = *reinterpret_cast<const ushort4*>(xr + 4 * q);
      acc[4*q+0] = wself * bf2f(xv.x);
      acc[4*q+1] = wself * bf2f(xv.y);
      acc[4*q+2] = wself * bf2f(xv.z);
      acc[4*q+3] = wself * bf2f(xv.w);
    }
  }

  for (int k = beg; k < end; ++k) {
    int sj = srcs[k];
    float w = expf(lrelu(a_s[sj] + adi) - m) * inv;
    const unsigned short* xr = xcol + (size_t)sj * XBS;
    #pragma unroll
    for (int q = 0; q < 5; ++q) {
      ushort4 xv = *reinterpret_cast<const ushort4*>(xr + 4 * q);
      acc[4*q+0] += w * bf2f(xv.x);
      acc[4*q+1] += w * bf2f(xv.y);
      acc[4*q+2] += w * bf2f(xv.z);
      acc[4*q+3] += w * bf2f(xv.w);
    }
  }
  float* op = out + (size_t)node * OUT_DIM + 20u * cc;
  const float* bp = bias + 20u * cc;
  #pragma unroll
  for (int q = 0; q < 5; ++q) {
    float4 b = *reinterpret_cast<const float4*>(bp + 4 * q);
    float4 o = {acc[4*q] + b.x, acc[4*q+1] + b.y, acc[4*q+2] + b.z, acc[4*q+3] + b.w};
    *reinterpret_cast<float4*>(op + 4 * q) = o;
  }
}

extern "C" void kernel_launch(void* const* d_in, const int* in_sizes, int n_in,
                              void* d_out, int out_size, void* d_ws, size_t ws_size,
                              hipStream_t stream) {
  const float* z     = (const float*)d_in[0];
  const int*   ei    = (const int*)d_in[1];     // int64 in ref -> int32 on the wire
  const float* W     = (const float*)d_in[2];
  const float* att_s = (const float*)d_in[3];
  const float* att_d = (const float*)d_in[4];
  const float* bias  = (const float*)d_in[5];
  float* out = (float*)d_out;

  char* ws = (char*)d_ws;
  size_t off = 0;
  unsigned short* xb = (unsigned short*)(ws + off); off += (size_t)N_NODES * XBS * 2;  // 30.4 MB
  unsigned short* Wb = (unsigned short*)(ws + off); off += (size_t)BNP * KP * 2;
  float*  a_s  = (float*)(ws + off);  off += 50048 * 4;
  float*  a_d  = (float*)(ws + off);  off += 50048 * 4;
  int*    deg  = (int*)(ws + off);    off += 50048 * 4;
  int*    offs = (int*)(ws + off);    off += 50056 * 4;
  int*    cur  = (int*)(ws + off);    off += 50048 * 4;
  int*    bsum = (int*)(ws + off);    off += 64 * 4;
  int*    bex  = (int*)(ws + off);    off += 64 * 4;
  int*    srcs = (int*)(ws + off);    off += (size_t)N_EDGES * 4;
  float2* minv = (float2*)(ws + off); off += (size_t)50048 * 8;

  (void)hipMemsetAsync(deg, 0, N_NODES * 4, stream);
  (void)hipMemsetAsync(a_s, 0, 2 * 50048 * 4, stream);   // a_s + a_d (adjacent)

  wconv<<<(BNP * KP / 8 + 255) / 256, 256, 0, stream>>>(W, Wb);
  gemm_x<<<GRID_G, 256, 0, stream>>>(z, Wb, att_s, att_d, xb, a_s, a_d);
  hist<<<(N_EDGES + 255) / 256, 256, 0, stream>>>(ei, deg);
  scan1<<<NBLK, SCAN_B, 0, stream>>>(deg, bsum);
  scan2<<<1, 64, 0, stream>>>(bsum, bex, offs);
  scan3<<<NBLK, SCAN_B, 0, stream>>>(deg, bex, offs, cur);
  fill<<<(N_EDGES + 255) / 256, 256, 0, stream>>>(ei, cur, srcs);
  minv_k<<<(N_NODES + 3) / 4, 256, 0, stream>>>(a_s, a_d, offs, srcs, minv);
  aggregate<<<((unsigned)N_NODES * CCH + 255) / 256, 256, 0, stream>>>(
      xb, a_s, a_d, minv, offs, srcs, bias, out);
}

// Round 12
// 338.565 us; speedup vs baseline: 1.0579x; 1.0579x over previous
//
#include <hip/hip_runtime.h>

#define N_NODES 50000
#define N_EDGES 800000
#define IN_DIM  1200
#define KP      1216               // Wb padded K
#define OUT_DIM 300
#define BNP     320                // Wb padded rows
#define XBS     304                // xb row stride (bf16)
#define BM      64
#define NKT     38                 // K-steps of 32
#define GRID_M  ((N_NODES + BM - 1) / BM)   // 782

typedef __attribute__((ext_vector_type(8))) short short8;
typedef __attribute__((ext_vector_type(4))) float f32x4;

__device__ __forceinline__ short f2bf(float f) {
  unsigned u = __builtin_bit_cast(unsigned, f);
  u += 0x7fffu + ((u >> 16) & 1u);            // RNE
  return (short)(u >> 16);
}
__device__ __forceinline__ float bf2f(unsigned short h) {
  return __builtin_bit_cast(float, (unsigned)h << 16);
}
__device__ __forceinline__ float lrelu(float v) { return v > 0.f ? v : 0.2f * v; }

__device__ __forceinline__ float wredMaxF(float v) {
  #pragma unroll
  for (int o = 32; o > 0; o >>= 1) v = fmaxf(v, __shfl_xor(v, o));
  return v;
}
__device__ __forceinline__ float wredSumF(float v) {
  #pragma unroll
  for (int o = 32; o > 0; o >>= 1) v += __shfl_xor(v, o);
  return v;
}

// async 16B/lane global->LDS DMA; lds dest wave-uniform (HW adds lane*16)
__device__ __forceinline__ void gl_lds16(const unsigned short* g, unsigned short* l) {
  __builtin_amdgcn_global_load_lds(
      (const __attribute__((address_space(1))) unsigned int*)g,
      (__attribute__((address_space(3))) unsigned int*)l, 16, 0, 0);
}

// ---------------- W -> bf16, padded [320][1216]
__global__ __launch_bounds__(256) void wconv(const float* __restrict__ W,
                                             unsigned short* __restrict__ Wb) {
  int f = blockIdx.x * 256 + threadIdx.x;
  if (f >= BNP * KP / 8) return;
  int n = (f * 8) / KP, c = (f * 8) % KP;
  short8 v = {0,0,0,0,0,0,0,0};
  if (n < OUT_DIM && c < IN_DIM) {
    const float4* p = reinterpret_cast<const float4*>(W + (size_t)n * IN_DIM + c);
    float4 f0 = p[0], f1 = p[1];
    v[0]=f2bf(f0.x); v[1]=f2bf(f0.y); v[2]=f2bf(f0.z); v[3]=f2bf(f0.w);
    v[4]=f2bf(f1.x); v[5]=f2bf(f1.y); v[6]=f2bf(f1.z); v[7]=f2bf(f1.w);
  }
  *reinterpret_cast<short8*>(&Wb[(size_t)n * KP + c]) = v;
}

// ---------------- GEMM: xb = z @ W^T. BM=64, BN=320, BK=32, 4 waves (N-split).
// R10 geometry (refchecked, 0 bank conflicts) + T4 counted-vmcnt schedule:
// per step, issue DMA[k+1] then z[k+2]; end-of-step waits vmcnt(2) ONLY
// (z[k+2] stays in flight across the raw s_barrier). 2-deep z in named regs.
__global__ __launch_bounds__(256) void gemm_x(const float* __restrict__ z,
                                              const unsigned short* __restrict__ Wb,
                                              const float* __restrict__ att_s,
                                              const float* __restrict__ att_d,
                                              unsigned short* __restrict__ xb,
                                              float* __restrict__ a_s,
                                              float* __restrict__ a_d) {
  __shared__ __align__(16) unsigned short As[2][BM * 32];     // 2 x 4 KB
  __shared__ __align__(16) unsigned short Bs[2][BNP * 32];    // 2 x 20 KB

  const int tid  = threadIdx.x;
  const int lane = tid & 63;
  const int wid  = tid >> 6;           // 0..3, owns cols 80*wid..
  const int lr   = lane & 15;
  const int lg   = lane >> 4;
  const int lrs  = (lr >> 1) & 3;      // read-side swizzle term
  const int m0   = blockIdx.x * BM;

  f32x4 zero4 = {0.f, 0.f, 0.f, 0.f};
  const float4 fz4 = make_float4(0.f, 0.f, 0.f, 0.f);
  f32x4 acc[4][5];
  #pragma unroll
  for (int mf = 0; mf < 4; ++mf)
    #pragma unroll
    for (int nj = 0; nj < 5; ++nj) acc[mf][nj] = zero4;

  // A stage: thread -> row ra (0..63), logical chunk kaL, physical kaP
  const int ra  = tid >> 2;
  const int kaL = tid & 3;
  const int kaP = kaL ^ ((ra >> 1) & 3);
  const int am  = m0 + ra;
  const int amc = am < N_NODES ? am : N_NODES - 1;   // clamped row (always load)
  const bool mok = am < N_NODES;

  // two named z-register sets (2-deep prefetch; no runtime indexing: rule #20)
  float4 gA0, gA1, gB0, gB1;

  // B DMA: lane l -> row j*64 + wid*16 + (l>>2), phys chunk l&3;
  // global source pre-swizzled: chunk (l&3) ^ ((l>>3)&3).
  const int bgc = (lane & 3) ^ ((lane >> 3) & 3);

  // clamped z load: ALWAYS issues 2 vmem ops per thread (uniform vmcnt count)
  #define LOADA(G0, G1, KT)                                                   \
    {                                                                         \
      int k = (KT) * 32 + kaL * 8;                                            \
      int kc = k > (IN_DIM - 8) ? (IN_DIM - 8) : k;                           \
      const float4* p = reinterpret_cast<const float4*>(z + (size_t)amc * IN_DIM + kc); \
      G0 = p[0]; G1 = p[1];                                                   \
    }

  #define WRITEA(BUF, G0, G1, KT)                                             \
    {                                                                         \
      bool ok = mok && ((KT) * 32 + kaL * 8 + 8 <= IN_DIM);                   \
      float4 f0 = ok ? G0 : fz4, f1 = ok ? G1 : fz4;                          \
      short8 v;                                                               \
      v[0]=f2bf(f0.x); v[1]=f2bf(f0.y); v[2]=f2bf(f0.z); v[3]=f2bf(f0.w);     \
      v[4]=f2bf(f1.x); v[5]=f2bf(f1.y); v[6]=f2bf(f1.z); v[7]=f2bf(f1.w);     \
      *reinterpret_cast<short8*>(&As[BUF][ra * 32 + kaP * 8]) = v;            \
    }

  #define STAGEB(BUF, KT)                                                     \
    _Pragma("unroll")                                                         \
    for (int j = 0; j < 5; ++j) {                                             \
      const unsigned short* gsrc =                                            \
          Wb + (size_t)(j * 64 + wid * 16 + (lane >> 2)) * KP + (KT) * 32 + bgc * 8; \
      gl_lds16(gsrc, &Bs[BUF][(j * 64 + wid * 16) * 32]);                     \
    }

  #define COMPUTE(CUR)                                                        \
    {                                                                         \
      short8 a0_ = *reinterpret_cast<const short8*>(&As[CUR][(lr) * 32 + (lg ^ lrs) * 8]);        \
      short8 a1_ = *reinterpret_cast<const short8*>(&As[CUR][(16 + lr) * 32 + (lg ^ lrs) * 8]);   \
      short8 a2_ = *reinterpret_cast<const short8*>(&As[CUR][(32 + lr) * 32 + (lg ^ lrs) * 8]);   \
      short8 a3_ = *reinterpret_cast<const short8*>(&As[CUR][(48 + lr) * 32 + (lg ^ lrs) * 8]);   \
      _Pragma("unroll")                                                       \
      for (int nj = 0; nj < 5; ++nj) {                                        \
        short8 b = *reinterpret_cast<const short8*>(                          \
            &Bs[CUR][(wid * 80 + nj * 16 + lr) * 32 + (lg ^ lrs) * 8]);       \
        acc[0][nj] = __builtin_amdgcn_mfma_f32_16x16x32_bf16(a0_, b, acc[0][nj], 0, 0, 0); \
        acc[1][nj] = __builtin_amdgcn_mfma_f32_16x16x32_bf16(a1_, b, acc[1][nj], 0, 0, 0); \
        acc[2][nj] = __builtin_amdgcn_mfma_f32_16x16x32_bf16(a2_, b, acc[2][nj], 0, 0, 0); \
        acc[3][nj] = __builtin_amdgcn_mfma_f32_16x16x32_bf16(a3_, b, acc[3][nj], 0, 0, 0); \
      }                                                                       \
    }

  #define FENCE asm volatile("" ::: "memory")
  #define CBAR  asm volatile("s_waitcnt vmcnt(2) lgkmcnt(0)" ::: "memory");   \
                __builtin_amdgcn_s_barrier();                                 \
                asm volatile("" ::: "memory")

  // ---- prologue: queue = z[0](2), DMA[0](5), z[1](2)
  LOADA(gA0, gA1, 0);
  FENCE;
  STAGEB(0, 0);
  FENCE;
  LOADA(gB0, gB1, 1);
  FENCE;
  WRITEA(0, gA0, gA1, 0);            // compiler waits z[0]: vmcnt(7)
  CBAR;                              // retire DMA[0]; z[1] stays in flight

  // ---- main loop: steps 0..35 (paired, static reg-set/buffer indices)
  #pragma unroll 1
  for (int kt = 0; kt < 36; kt += 2) {
    // even step kt: compute buf0; stage DMA[kt+1]->buf1; issue z[kt+2]->setA
    STAGEB(1, kt + 1);
    FENCE;
    LOADA(gA0, gA1, kt + 2);
    FENCE;
    COMPUTE(0);
    WRITEA(1, gB0, gB1, kt + 1);     // consume z[kt+1] (vmcnt(7) auto)
    CBAR;                            // retire DMA[kt+1]; z[kt+2] survives

    // odd step kt+1: compute buf1; stage DMA[kt+2]->buf0; issue z[kt+3]->setB
    STAGEB(0, kt + 2);
    FENCE;
    LOADA(gB0, gB1, kt + 3);
    FENCE;
    COMPUTE(1);
    WRITEA(0, gA0, gA1, kt + 2);     // consume z[kt+2]
    CBAR;                            // retire DMA[kt+2]; z[kt+3] survives
  }

  // ---- peeled step 36 (buf0): stage DMA[37]; consume z[37]; full drain
  STAGEB(1, 37);
  FENCE;
  COMPUTE(0);
  WRITEA(1, gB0, gB1, 37);
  __syncthreads();                   // vmcnt(0): drains DMA[37] (nothing else left)

  // ---- peeled step 37 (buf1)
  COMPUTE(1);
  __syncthreads();

  #undef LOADA
  #undef WRITEA
  #undef STAGEB
  #undef COMPUTE
  #undef FENCE
  #undef CBAR

  // ---- epilogue: bf16 x store + fused logits, cross-wave (4 col-waves) reduce
  float* red = reinterpret_cast<float*>(&As[0][0]);  // [2 sd][4 wid][64 rows] = 2 KB

  float ps[4][4], pd[4][4];
  #pragma unroll
  for (int mf = 0; mf < 4; ++mf)
    #pragma unroll
    for (int jj = 0; jj < 4; ++jj) { ps[mf][jj] = 0.f; pd[mf][jj] = 0.f; }

  #pragma unroll
  for (int nj = 0; nj < 5; ++nj) {
    int c = wid * 80 + nj * 16 + lr;
    bool cv = c < OUT_DIM;
    float vs = cv ? att_s[c] : 0.f;
    float vd = cv ? att_d[c] : 0.f;
    #pragma unroll
    for (int mf = 0; mf < 4; ++mf) {
      #pragma unroll
      for (int jj = 0; jj < 4; ++jj) {
        float val = acc[mf][nj][jj];
        int r = m0 + mf * 16 + 4 * lg + jj;
        if (cv && r < N_NODES) xb[(size_t)r * XBS + c] = (unsigned short)f2bf(val);
        ps[mf][jj] += val * vs;
        pd[mf][jj] += val * vd;
      }
    }
  }
  #pragma unroll
  for (int mf = 0; mf < 4; ++mf)
    #pragma unroll
    for (int jj = 0; jj < 4; ++jj) {
      #pragma unroll
      for (int o = 8; o > 0; o >>= 1) {
        ps[mf][jj] += __shfl_xor(ps[mf][jj], o);
        pd[mf][jj] += __shfl_xor(pd[mf][jj], o);
      }
      if (lr == 0) {
        int rr = mf * 16 + 4 * lg + jj;
        red[wid * 64 + rr]       = ps[mf][jj];
        red[256 + wid * 64 + rr] = pd[mf][jj];
      }
    }
  __syncthreads();
  if (tid < 64) {
    int r = m0 + tid;
    if (r < N_NODES)
      a_s[r] = red[tid] + red[64 + tid] + red[128 + tid] + red[192 + tid];
  } else if (tid < 128) {
    int t = tid - 64, r = m0 + t;
    if (r < N_NODES)
      a_d[r] = red[256 + t] + red[256 + 64 + t] + red[256 + 128 + t] + red[256 + 192 + t];
  }
}

// ---------------- CSR build (edges only; self-loops handled analytically)
__global__ void hist(const int* __restrict__ ei, int* __restrict__ deg) {
  int e = blockIdx.x * blockDim.x + threadIdx.x;
  if (e < N_EDGES) {
    unsigned dst = (unsigned)ei[N_EDGES + e];
    if (dst < N_NODES) atomicAdd(&deg[dst], 1);
  }
}

#define SCAN_B 1024
#define NBLK   49

__global__ __launch_bounds__(SCAN_B) void scan1(const int* __restrict__ deg,
                                                int* __restrict__ bsum) {
  int i = blockIdx.x * SCAN_B + threadIdx.x;
  int v = (i < N_NODES) ? deg[i] : 0;
  #pragma unroll
  for (int o = 32; o > 0; o >>= 1) v += __shfl_xor(v, o);
  __shared__ int wt[16];
  if ((threadIdx.x & 63) == 0) wt[threadIdx.x >> 6] = v;
  __syncthreads();
  if (threadIdx.x == 0) {
    int t = 0;
    #pragma unroll
    for (int w = 0; w < 16; ++w) t += wt[w];
    bsum[blockIdx.x] = t;
  }
}

__global__ void scan2(const int* __restrict__ bsum, int* __restrict__ bex,
                      int* __restrict__ offs) {
  int l = threadIdx.x;
  int v = (l < NBLK) ? bsum[l] : 0;
  int incl = v;
  #pragma unroll
  for (int off = 1; off < 64; off <<= 1) {
    int u = __shfl_up(incl, off);
    if (l >= off) incl += u;
  }
  if (l < NBLK) bex[l] = incl - v;
  if (l == NBLK - 1) offs[N_NODES] = incl;
}

__global__ __launch_bounds__(SCAN_B) void scan3(const int* __restrict__ deg,
                                                const int* __restrict__ bex,
                                                int* __restrict__ offs,
                                                int* __restrict__ cursor) {
  int tid = threadIdx.x;
  int i = blockIdx.x * SCAN_B + tid;
  int lane = tid & 63, wid = tid >> 6;
  int v = (i < N_NODES) ? deg[i] : 0;
  int incl = v;
  #pragma unroll
  for (int off = 1; off < 64; off <<= 1) {
    int u = __shfl_up(incl, off);
    if (lane >= off) incl += u;
  }
  __shared__ int wt[16];
  if (lane == 63) wt[wid] = incl;
  __syncthreads();
  if (tid < 16) {
    int t = wt[tid];
    int sc = t;
    #pragma unroll
    for (int off = 1; off < 16; off <<= 1) {
      int u = __shfl_up(sc, off);
      if (tid >= off) sc += u;
    }
    wt[tid] = sc - t;
  }
  __syncthreads();
  int excl = incl - v + wt[wid] + bex[blockIdx.x];
  if (i < N_NODES) { offs[i] = excl; cursor[i] = excl; }
}

__global__ void fill(const int* __restrict__ ei, int* __restrict__ cursor,
                     int* __restrict__ srcs) {
  int e = blockIdx.x * blockDim.x + threadIdx.x;
  if (e < N_EDGES) {
    unsigned dst = (unsigned)ei[N_EDGES + e];
    unsigned src = (unsigned)ei[e];
    if (dst < N_NODES && src < N_NODES) {
      int pos = atomicAdd(&cursor[dst], 1);
      srcs[pos] = (int)src;
    }
  }
}

// ---------------- per-node softmax stats (m, 1/s) — wave per node
__global__ __launch_bounds__(256) void minv_k(const float* __restrict__ a_s,
                                              const float* __restrict__ a_d,
                                              const int* __restrict__ offs,
                                              const int* __restrict__ srcs,
                                              float2* __restrict__ minv) {
  int node = blockIdx.x * 4 + (threadIdx.x >> 6);
  if (node >= N_NODES) return;
  int lane = threadIdx.x & 63;
  int beg = offs[node], end = offs[node + 1];
  float adi = a_d[node];
  float eself = lrelu(a_s[node] + adi);

  float m = eself;
  for (int k = beg + lane; k < end; k += 64)
    m = fmaxf(m, lrelu(a_s[srcs[k]] + adi));
  m = wredMaxF(m);

  float s = 0.f;
  for (int k = beg + lane; k < end; k += 64)
    s += expf(lrelu(a_s[srcs[k]] + adi) - m);
  s = wredSumF(s) + expf(eself - m);
  if (lane == 0) minv[node] = make_float2(m, 1.0f / s);
}

// ---------------- streaming weighted gather: thread = (node, 20-col chunk)
#define CCH 15
__global__ __launch_bounds__(256) void aggregate(const unsigned short* __restrict__ xb,
                                                 const float* __restrict__ a_s,
                                                 const float* __restrict__ a_d,
                                                 const float2* __restrict__ minv,
                                                 const int* __restrict__ offs,
                                                 const int* __restrict__ srcs,
                                                 const float* __restrict__ bias,
                                                 float* __restrict__ out) {
  unsigned wi = blockIdx.x * 256u + threadIdx.x;
  if (wi >= (unsigned)N_NODES * CCH) return;
  unsigned node = wi / CCH;
  unsigned cc = wi - node * CCH;           // cols 20cc..20cc+19

  int beg = offs[node], end = offs[node + 1];
  float2 mi = minv[node];
  const float m = mi.x, inv = mi.y;
  const float adi = a_d[node];
  const float wself = expf(lrelu(a_s[node] + adi) - m) * inv;

  const unsigned short* xcol = xb + 20u * cc;

  float acc[20];
  {
    const unsigned short* xr = xcol + (size_t)node * XBS;
    #pragma unroll
    for (int q = 0; q < 5; ++q) {
      ushort4 xv = *reinterpret_cast<const ushort4*>(xr + 4 * q);
      acc[4*q+0] = wself * bf2f(xv.x);
      acc[4*q+1] = wself * bf2f(xv.y);
      acc[4*q+2] = wself * bf2f(xv.z);
      acc[4*q+3] = wself * bf2f(xv.w);
    }
  }

  for (int k = beg; k < end; ++k) {
    int sj = srcs[k];
    float w = expf(lrelu(a_s[sj] + adi) - m) * inv;
    const unsigned short* xr = xcol + (size_t)sj * XBS;
    #pragma unroll
    for (int q = 0; q < 5; ++q) {
      ushort4 xv = *reinterpret_cast<const ushort4*>(xr + 4 * q);
      acc[4*q+0] += w * bf2f(xv.x);
      acc[4*q+1] += w * bf2f(xv.y);
      acc[4*q+2] += w * bf2f(xv.z);
      acc[4*q+3] += w * bf2f(xv.w);
    }
  }
  float* op = out + (size_t)node * OUT_DIM + 20u * cc;
  const float* bp = bias + 20u * cc;
  #pragma unroll
  for (int q = 0; q < 5; ++q) {
    float4 b = *reinterpret_cast<const float4*>(bp + 4 * q);
    float4 o = {acc[4*q] + b.x, acc[4*q+1] + b.y, acc[4*q+2] + b.z, acc[4*q+3] + b.w};
    *reinterpret_cast<float4*>(op + 4 * q) = o;
  }
}

extern "C" void kernel_launch(void* const* d_in, const int* in_sizes, int n_in,
                              void* d_out, int out_size, void* d_ws, size_t ws_size,
                              hipStream_t stream) {
  const float* z     = (const float*)d_in[0];
  const int*   ei    = (const int*)d_in[1];     // int64 in ref -> int32 on the wire
  const float* W     = (const float*)d_in[2];
  const float* att_s = (const float*)d_in[3];
  const float* att_d = (const float*)d_in[4];
  const float* bias  = (const float*)d_in[5];
  float* out = (float*)d_out;

  char* ws = (char*)d_ws;
  size_t off = 0;
  unsigned short* xb = (unsigned short*)(ws + off); off += (size_t)N_NODES * XBS * 2;  // 30.4 MB
  unsigned short* Wb = (unsigned short*)(ws + off); off += (size_t)BNP * KP * 2;
  float*  a_s  = (float*)(ws + off);  off += 50048 * 4;
  float*  a_d  = (float*)(ws + off);  off += 50048 * 4;
  int*    deg  = (int*)(ws + off);    off += 50048 * 4;
  int*    offs = (int*)(ws + off);    off += 50056 * 4;
  int*    cur  = (int*)(ws + off);    off += 50048 * 4;
  int*    bsum = (int*)(ws + off);    off += 64 * 4;
  int*    bex  = (int*)(ws + off);    off += 64 * 4;
  int*    srcs = (int*)(ws + off);    off += (size_t)N_EDGES * 4;
  float2* minv = (float2*)(ws + off); off += (size_t)50048 * 8;

  (void)hipMemsetAsync(deg, 0, N_NODES * 4, stream);

  wconv<<<(BNP * KP / 8 + 255) / 256, 256, 0, stream>>>(W, Wb);
  gemm_x<<<GRID_M, 256, 0, stream>>>(z, Wb, att_s, att_d, xb, a_s, a_d);
  hist<<<(N_EDGES + 255) / 256, 256, 0, stream>>>(ei, deg);
  scan1<<<NBLK, SCAN_B, 0, stream>>>(deg, bsum);
  scan2<<<1, 64, 0, stream>>>(bsum, bex, offs);
  scan3<<<NBLK, SCAN_B, 0, stream>>>(deg, bex, offs, cur);
  fill<<<(N_EDGES + 255) / 256, 256, 0, stream>>>(ei, cur, srcs);
  minv_k<<<(N_NODES + 3) / 4, 256, 0, stream>>>(a_s, a_d, offs, srcs, minv);
  aggregate<<<((unsigned)N_NODES * CCH + 255) / 256, 256, 0, stream>>>(
      xb, a_s, a_d, minv, offs, srcs, bias, out);
}

// Round 13
// 332.012 us; speedup vs baseline: 1.0788x; 1.0197x over previous
//
#include <hip/hip_runtime.h>

#define N_NODES 50000
#define N_EDGES 800000
#define IN_DIM  1200
#define KP      1216               // Wb padded K
#define OUT_DIM 300
#define BNP     320                // Wb padded rows
#define XBS     304                // xb row stride (bf16)
#define BM      128
#define NKT     38                 // K-steps of 32
#define GRID_M  ((N_NODES + BM - 1) / BM)   // 391

typedef __attribute__((ext_vector_type(8))) short short8;
typedef __attribute__((ext_vector_type(4))) float f32x4;

__device__ __forceinline__ short f2bf(float f) {
  unsigned u = __builtin_bit_cast(unsigned, f);
  u += 0x7fffu + ((u >> 16) & 1u);            // RNE
  return (short)(u >> 16);
}
__device__ __forceinline__ float bf2f(unsigned short h) {
  return __builtin_bit_cast(float, (unsigned)h << 16);
}
__device__ __forceinline__ float lrelu(float v) { return v > 0.f ? v : 0.2f * v; }

__device__ __forceinline__ float wredMaxF(float v) {
  #pragma unroll
  for (int o = 32; o > 0; o >>= 1) v = fmaxf(v, __shfl_xor(v, o));
  return v;
}
__device__ __forceinline__ float wredSumF(float v) {
  #pragma unroll
  for (int o = 32; o > 0; o >>= 1) v += __shfl_xor(v, o);
  return v;
}

// async 16B/lane global->LDS DMA; lds dest wave-uniform (HW adds lane*16)
__device__ __forceinline__ void gl_lds16(const unsigned short* g, unsigned short* l) {
  __builtin_amdgcn_global_load_lds(
      (const __attribute__((address_space(1))) unsigned int*)g,
      (__attribute__((address_space(3))) unsigned int*)l, 16, 0, 0);
}

// ---------------- W -> bf16, padded [320][1216]
__global__ __launch_bounds__(256) void wconv(const float* __restrict__ W,
                                             unsigned short* __restrict__ Wb) {
  int f = blockIdx.x * 256 + threadIdx.x;
  if (f >= BNP * KP / 8) return;
  int n = (f * 8) / KP, c = (f * 8) % KP;
  short8 v = {0,0,0,0,0,0,0,0};
  if (n < OUT_DIM && c < IN_DIM) {
    const float4* p = reinterpret_cast<const float4*>(W + (size_t)n * IN_DIM + c);
    float4 f0 = p[0], f1 = p[1];
    v[0]=f2bf(f0.x); v[1]=f2bf(f0.y); v[2]=f2bf(f0.z); v[3]=f2bf(f0.w);
    v[4]=f2bf(f1.x); v[5]=f2bf(f1.y); v[6]=f2bf(f1.z); v[7]=f2bf(f1.w);
  }
  *reinterpret_cast<short8*>(&Wb[(size_t)n * KP + c]) = v;
}

// ---------------- GEMM: xb = z @ W^T. BM=128, BN=320, BK=32, 8 waves (2Mw x 4Nw).
// Grid halved to 391 (block-step wall is ~constant: fewer steps in flight wins).
// Wave = 4 M-frags x 5 N-frags. B via global_load_lds DMA + verified R10 swizzle
// (0 conflicts); A reg-staged f32->bf16. One __syncthreads per step, issue-early.
__global__ __launch_bounds__(512) void gemm_x(const float* __restrict__ z,
                                              const unsigned short* __restrict__ Wb,
                                              const float* __restrict__ att_s,
                                              const float* __restrict__ att_d,
                                              unsigned short* __restrict__ xb,
                                              float* __restrict__ a_s,
                                              float* __restrict__ a_d) {
  __shared__ __align__(16) unsigned short As[2][BM * 32];     // 2 x 8 KB
  __shared__ __align__(16) unsigned short Bs[2][BNP * 32];    // 2 x 20 KB

  const int tid  = threadIdx.x;
  const int lane = tid & 63;
  const int wid  = tid >> 6;           // 0..7
  const int mw   = wid >> 2;           // 0..1: rows mw*64..
  const int nw   = wid & 3;            // 0..3: cols nw*80..
  const int lr   = lane & 15;
  const int lg   = lane >> 4;
  const int lrs  = (lr >> 1) & 3;      // read-side swizzle term
  const int m0   = blockIdx.x * BM;

  f32x4 zero4 = {0.f, 0.f, 0.f, 0.f};
  const float4 fz4 = make_float4(0.f, 0.f, 0.f, 0.f);
  f32x4 acc[4][5];
  #pragma unroll
  for (int mf = 0; mf < 4; ++mf)
    #pragma unroll
    for (int nj = 0; nj < 5; ++nj) acc[mf][nj] = zero4;

  // A stage: thread -> row ra (0..127), logical chunk kaL, physical kaP
  const int ra  = tid >> 2;
  const int kaL = tid & 3;
  const int kaP = kaL ^ ((ra >> 1) & 3);
  const int am  = m0 + ra;
  float4 ga0, ga1;

  // B DMA: 20 row-groups of 16; wave w covers j = w, w+8, w+16 (j<20).
  // lane l -> row j*16 + (l>>2), phys chunk l&3; global source pre-swizzled.
  const int bgc = (lane & 3) ^ ((lane >> 3) & 3);

  #define LOADA(KT)                                                           \
    {                                                                         \
      int k = (KT) * 32 + kaL * 8;                                            \
      if (am < N_NODES && k + 8 <= IN_DIM) {                                  \
        const float4* p = reinterpret_cast<const float4*>(z + (size_t)am * IN_DIM + k); \
        ga0 = p[0]; ga1 = p[1];                                               \
      } else { ga0 = fz4; ga1 = fz4; }                                        \
    }

  #define WRITEA(BUF)                                                         \
    {                                                                         \
      short8 v;                                                               \
      v[0]=f2bf(ga0.x); v[1]=f2bf(ga0.y); v[2]=f2bf(ga0.z); v[3]=f2bf(ga0.w); \
      v[4]=f2bf(ga1.x); v[5]=f2bf(ga1.y); v[6]=f2bf(ga1.z); v[7]=f2bf(ga1.w); \
      *reinterpret_cast<short8*>(&As[BUF][ra * 32 + kaP * 8]) = v;            \
    }

  #define STAGEB(BUF, KT)                                                     \
    _Pragma("unroll")                                                         \
    for (int t5 = 0; t5 < 3; ++t5) {                                          \
      int j = wid + 8 * t5;                                                   \
      if (j < 20) {                                                           \
        const unsigned short* gsrc =                                          \
            Wb + (size_t)(j * 16 + (lane >> 2)) * KP + (KT) * 32 + bgc * 8;   \
        gl_lds16(gsrc, &Bs[BUF][j * 16 * 32]);                                \
      }                                                                       \
    }

  STAGEB(0, 0);
  LOADA(0);
  WRITEA(0);
  __syncthreads();

  #pragma unroll 1
  for (int kt = 0; kt < NKT; ++kt) {
    const int cur = kt & 1;
    if (kt < NKT - 1) {
      STAGEB(cur ^ 1, kt + 1);       // async DMA toward other buffer
      LOADA(kt + 1);                 // z load in flight across compute
    }

    // A frags: row = mw*64 + mf*16 + lr; phys chunk = lg ^ lrs
    short8 a0 = *reinterpret_cast<const short8*>(&As[cur][(mw * 64 +      lr) * 32 + (lg ^ lrs) * 8]);
    short8 a1 = *reinterpret_cast<const short8*>(&As[cur][(mw * 64 + 16 + lr) * 32 + (lg ^ lrs) * 8]);
    short8 a2 = *reinterpret_cast<const short8*>(&As[cur][(mw * 64 + 32 + lr) * 32 + (lg ^ lrs) * 8]);
    short8 a3 = *reinterpret_cast<const short8*>(&As[cur][(mw * 64 + 48 + lr) * 32 + (lg ^ lrs) * 8]);
    // B frags: row = nw*80 + nj*16 + lr
    #pragma unroll
    for (int nj = 0; nj < 5; ++nj) {
      short8 b = *reinterpret_cast<const short8*>(
          &Bs[cur][(nw * 80 + nj * 16 + lr) * 32 + (lg ^ lrs) * 8]);
      acc[0][nj] = __builtin_amdgcn_mfma_f32_16x16x32_bf16(a0, b, acc[0][nj], 0, 0, 0);
      acc[1][nj] = __builtin_amdgcn_mfma_f32_16x16x32_bf16(a1, b, acc[1][nj], 0, 0, 0);
      acc[2][nj] = __builtin_amdgcn_mfma_f32_16x16x32_bf16(a2, b, acc[2][nj], 0, 0, 0);
      acc[3][nj] = __builtin_amdgcn_mfma_f32_16x16x32_bf16(a3, b, acc[3][nj], 0, 0, 0);
    }

    if (kt < NKT - 1) { WRITEA(cur ^ 1); }
    __syncthreads();                 // drains DMA + A write, releases cur
  }
  #undef LOADA
  #undef WRITEA
  #undef STAGEB

  // ---- epilogue: bf16 x store + fused logits; reduce across 4 nw-waves via LDS
  float* red = reinterpret_cast<float*>(&As[0][0]);  // [2 sd][4 nw][128 rows] = 4 KB

  float ps[4][4], pd[4][4];
  #pragma unroll
  for (int mf = 0; mf < 4; ++mf)
    #pragma unroll
    for (int jj = 0; jj < 4; ++jj) { ps[mf][jj] = 0.f; pd[mf][jj] = 0.f; }

  #pragma unroll
  for (int nj = 0; nj < 5; ++nj) {
    int c = nw * 80 + nj * 16 + lr;
    bool cv = c < OUT_DIM;
    float vs = cv ? att_s[c] : 0.f;
    float vd = cv ? att_d[c] : 0.f;
    #pragma unroll
    for (int mf = 0; mf < 4; ++mf) {
      #pragma unroll
      for (int jj = 0; jj < 4; ++jj) {
        float val = acc[mf][nj][jj];
        int r = m0 + mw * 64 + mf * 16 + 4 * lg + jj;
        if (cv && r < N_NODES) xb[(size_t)r * XBS + c] = (unsigned short)f2bf(val);
        ps[mf][jj] += val * vs;
        pd[mf][jj] += val * vd;
      }
    }
  }
  #pragma unroll
  for (int mf = 0; mf < 4; ++mf)
    #pragma unroll
    for (int jj = 0; jj < 4; ++jj) {
      #pragma unroll
      for (int o = 8; o > 0; o >>= 1) {
        ps[mf][jj] += __shfl_xor(ps[mf][jj], o);
        pd[mf][jj] += __shfl_xor(pd[mf][jj], o);
      }
      if (lr == 0) {
        int rr = mw * 64 + mf * 16 + 4 * lg + jj;   // 0..127
        red[nw * 128 + rr]       = ps[mf][jj];
        red[512 + nw * 128 + rr] = pd[mf][jj];
      }
    }
  __syncthreads();
  if (tid < 128) {
    int r = m0 + tid;
    if (r < N_NODES)
      a_s[r] = red[tid] + red[128 + tid] + red[256 + tid] + red[384 + tid];
  } else if (tid < 256) {
    int t = tid - 128, r = m0 + t;
    if (r < N_NODES)
      a_d[r] = red[512 + t] + red[512 + 128 + t] + red[512 + 256 + t] + red[512 + 384 + t];
  }
}

// ---------------- CSR build (edges only; self-loops handled analytically)
__global__ void hist(const int* __restrict__ ei, int* __restrict__ deg) {
  int e = blockIdx.x * blockDim.x + threadIdx.x;
  if (e < N_EDGES) {
    unsigned dst = (unsigned)ei[N_EDGES + e];
    if (dst < N_NODES) atomicAdd(&deg[dst], 1);
  }
}

#define SCAN_B 1024
#define NBLK   49

__global__ __launch_bounds__(SCAN_B) void scan1(const int* __restrict__ deg,
                                                int* __restrict__ bsum) {
  int i = blockIdx.x * SCAN_B + threadIdx.x;
  int v = (i < N_NODES) ? deg[i] : 0;
  #pragma unroll
  for (int o = 32; o > 0; o >>= 1) v += __shfl_xor(v, o);
  __shared__ int wt[16];
  if ((threadIdx.x & 63) == 0) wt[threadIdx.x >> 6] = v;
  __syncthreads();
  if (threadIdx.x == 0) {
    int t = 0;
    #pragma unroll
    for (int w = 0; w < 16; ++w) t += wt[w];
    bsum[blockIdx.x] = t;
  }
}

__global__ void scan2(const int* __restrict__ bsum, int* __restrict__ bex,
                      int* __restrict__ offs) {
  int l = threadIdx.x;
  int v = (l < NBLK) ? bsum[l] : 0;
  int incl = v;
  #pragma unroll
  for (int off = 1; off < 64; off <<= 1) {
    int u = __shfl_up(incl, off);
    if (l >= off) incl += u;
  }
  if (l < NBLK) bex[l] = incl - v;
  if (l == NBLK - 1) offs[N_NODES] = incl;
}

__global__ __launch_bounds__(SCAN_B) void scan3(const int* __restrict__ deg,
                                                const int* __restrict__ bex,
                                                int* __restrict__ offs,
                                                int* __restrict__ cursor) {
  int tid = threadIdx.x;
  int i = blockIdx.x * SCAN_B + tid;
  int lane = tid & 63, wid = tid >> 6;
  int v = (i < N_NODES) ? deg[i] : 0;
  int incl = v;
  #pragma unroll
  for (int off = 1; off < 64; off <<= 1) {
    int u = __shfl_up(incl, off);
    if (lane >= off) incl += u;
  }
  __shared__ int wt[16];
  if (lane == 63) wt[wid] = incl;
  __syncthreads();
  if (tid < 16) {
    int t = wt[tid];
    int sc = t;
    #pragma unroll
    for (int off = 1; off < 16; off <<= 1) {
      int u = __shfl_up(sc, off);
      if (tid >= off) sc += u;
    }
    wt[tid] = sc - t;
  }
  __syncthreads();
  int excl = incl - v + wt[wid] + bex[blockIdx.x];
  if (i < N_NODES) { offs[i] = excl; cursor[i] = excl; }
}

__global__ void fill(const int* __restrict__ ei, int* __restrict__ cursor,
                     int* __restrict__ srcs) {
  int e = blockIdx.x * blockDim.x + threadIdx.x;
  if (e < N_EDGES) {
    unsigned dst = (unsigned)ei[N_EDGES + e];
    unsigned src = (unsigned)ei[e];
    if (dst < N_NODES && src < N_NODES) {
      int pos = atomicAdd(&cursor[dst], 1);
      srcs[pos] = (int)src;
    }
  }
}

// ---------------- per-node softmax stats (m, 1/s) — wave per node
__global__ __launch_bounds__(256) void minv_k(const float* __restrict__ a_s,
                                              const float* __restrict__ a_d,
                                              const int* __restrict__ offs,
                                              const int* __restrict__ srcs,
                                              float2* __restrict__ minv) {
  int node = blockIdx.x * 4 + (threadIdx.x >> 6);
  if (node >= N_NODES) return;
  int lane = threadIdx.x & 63;
  int beg = offs[node], end = offs[node + 1];
  float adi = a_d[node];
  float eself = lrelu(a_s[node] + adi);

  float m = eself;
  for (int k = beg + lane; k < end; k += 64)
    m = fmaxf(m, lrelu(a_s[srcs[k]] + adi));
  m = wredMaxF(m);

  float s = 0.f;
  for (int k = beg + lane; k < end; k += 64)
    s += expf(lrelu(a_s[srcs[k]] + adi) - m);
  s = wredSumF(s) + expf(eself - m);
  if (lane == 0) minv[node] = make_float2(m, 1.0f / s);
}

// ---------------- streaming weighted gather: thread = (node, 20-col chunk)
#define CCH 15
__global__ __launch_bounds__(256) void aggregate(const unsigned short* __restrict__ xb,
                                                 const float* __restrict__ a_s,
                                                 const float* __restrict__ a_d,
                                                 const float2* __restrict__ minv,
                                                 const int* __restrict__ offs,
                                                 const int* __restrict__ srcs,
                                                 const float* __restrict__ bias,
                                                 float* __restrict__ out) {
  unsigned wi = blockIdx.x * 256u + threadIdx.x;
  if (wi >= (unsigned)N_NODES * CCH) return;
  unsigned node = wi / CCH;
  unsigned cc = wi - node * CCH;           // cols 20cc..20cc+19

  int beg = offs[node], end = offs[node + 1];
  float2 mi = minv[node];
  const float m = mi.x, inv = mi.y;
  const float adi = a_d[node];
  const float wself = expf(lrelu(a_s[node] + adi) - m) * inv;

  const unsigned short* xcol = xb + 20u * cc;

  float acc[20];
  {
    const unsigned short* xr = xcol + (size_t)node * XBS;
    #pragma unroll
    for (int q = 0; q < 5; ++q) {
      ushort4 xv = *reinterpret_cast<const ushort4*>(xr + 4 * q);
      acc[4*q+0] = wself * bf2f(xv.x);
      acc[4*q+1] = wself * bf2f(xv.y);
      acc[4*q+2] = wself * bf2f(xv.z);
      acc[4*q+3] = wself * bf2f(xv.w);
    }
  }

  for (int k = beg; k < end; ++k) {
    int sj = srcs[k];
    float w = expf(lrelu(a_s[sj] + adi) - m) * inv;
    const unsigned short* xr = xcol + (size_t)sj * XBS;
    #pragma unroll
    for (int q = 0; q < 5; ++q) {
      ushort4 xv = *reinterpret_cast<const ushort4*>(xr + 4 * q);
      acc[4*q+0] += w * bf2f(xv.x);
      acc[4*q+1] += w * bf2f(xv.y);
      acc[4*q+2] += w * bf2f(xv.z);
      acc[4*q+3] += w * bf2f(xv.w);
    }
  }
  float* op = out + (size_t)node * OUT_DIM + 20u * cc;
  const float* bp = bias + 20u * cc;
  #pragma unroll
  for (int q = 0; q < 5; ++q) {
    float4 b = *reinterpret_cast<const float4*>(bp + 4 * q);
    float4 o = {acc[4*q] + b.x, acc[4*q+1] + b.y, acc[4*q+2] + b.z, acc[4*q+3] + b.w};
    *reinterpret_cast<float4*>(op + 4 * q) = o;
  }
}

extern "C" void kernel_launch(void* const* d_in, const int* in_sizes, int n_in,
                              void* d_out, int out_size, void* d_ws, size_t ws_size,
                              hipStream_t stream) {
  const float* z     = (const float*)d_in[0];
  const int*   ei    = (const int*)d_in[1];     // int64 in ref -> int32 on the wire
  const float* W     = (const float*)d_in[2];
  const float* att_s = (const float*)d_in[3];
  const float* att_d = (const float*)d_in[4];
  const float* bias  = (const float*)d_in[5];
  float* out = (float*)d_out;

  char* ws = (char*)d_ws;
  size_t off = 0;
  unsigned short* xb = (unsigned short*)(ws + off); off += (size_t)N_NODES * XBS * 2;  // 30.4 MB
  unsigned short* Wb = (unsigned short*)(ws + off); off += (size_t)BNP * KP * 2;
  float*  a_s  = (float*)(ws + off);  off += 50048 * 4;
  float*  a_d  = (float*)(ws + off);  off += 50048 * 4;
  int*    deg  = (int*)(ws + off);    off += 50048 * 4;
  int*    offs = (int*)(ws + off);    off += 50056 * 4;
  int*    cur  = (int*)(ws + off);    off += 50048 * 4;
  int*    bsum = (int*)(ws + off);    off += 64 * 4;
  int*    bex  = (int*)(ws + off);    off += 64 * 4;
  int*    srcs = (int*)(ws + off);    off += (size_t)N_EDGES * 4;
  float2* minv = (float2*)(ws + off); off += (size_t)50048 * 8;

  (void)hipMemsetAsync(deg, 0, N_NODES * 4, stream);

  wconv<<<(BNP * KP / 8 + 255) / 256, 256, 0, stream>>>(W, Wb);
  gemm_x<<<GRID_M, 512, 0, stream>>>(z, Wb, att_s, att_d, xb, a_s, a_d);
  hist<<<(N_EDGES + 255) / 256, 256, 0, stream>>>(ei, deg);
  scan1<<<NBLK, SCAN_B, 0, stream>>>(deg, bsum);
  scan2<<<1, 64, 0, stream>>>(bsum, bex, offs);
  scan3<<<NBLK, SCAN_B, 0, stream>>>(deg, bex, offs, cur);
  fill<<<(N_EDGES + 255) / 256, 256, 0, stream>>>(ei, cur, srcs);
  minv_k<<<(N_NODES + 3) / 4, 256, 0, stream>>>(a_s, a_d, offs, srcs, minv);
  aggregate<<<((unsigned)N_NODES * CCH + 255) / 256, 256, 0, stream>>>(
      xb, a_s, a_d, minv, offs, srcs, bias, out);
}